// Round 9
// baseline (234.454 us; speedup 1.0000x reference)
//
#include <hip/hip_runtime.h>
#include <hip/hip_bf16.h>

// B=4, L=4096, C=1024, H=16, D=64
// GEMM1: qkv = x@Wqkv^T+b  (M=16384,N=3072,K=1024)  -> bf16
// attn: per-token 16x16 head-attention, writes scrambled layout
// GEMM2: out = scr@Wout^T+b (M=16384,N=1024,K=1024) -> fp32
//
// gemm256 (structure frozen since R7 at ~912 TF; R5-R7 schedule A/Bs all
// null): 256x256 tile, BK=64, 8 waves, 128KiB LDS dbuf, single-sync K-tile,
// counted vmcnt, XOR swizzle, setprio, XCD swizzle.
// Round-9: (a) SIMD-partner stagger — waves 4..7 (second wave on each SIMD)
// run quads in rotated order (A1-half first) so the two waves sharing a SIMD
// don't stall at the same instants; stages/barriers identical both paths.
// (b) attn: drop Pl LDS + 2nd syncthreads; PV via __shfl broadcast of
// in-register unnormalized e; LDS 30.6->26.6 KB = 5->6 blocks/CU (+20% TLP
// for a latency-bound kernel).

typedef __attribute__((ext_vector_type(8))) short bf16x8;
typedef __attribute__((ext_vector_type(4))) float f32x4;

__device__ __forceinline__ float bf2f(unsigned short u) {
    union { unsigned int i; float f; } x;
    x.i = ((unsigned int)u) << 16;
    return x.f;
}
__device__ __forceinline__ unsigned short f2bf(float f) {
    unsigned int u = __float_as_uint(f);
    u = (u + 0x7FFFu + ((u >> 16) & 1u)) >> 16;   // RNE
    return (unsigned short)u;
}

#define VMCNT4() asm volatile("s_waitcnt vmcnt(4)" ::: "memory")
#define VMCNT0() asm volatile("s_waitcnt vmcnt(0)" ::: "memory")
#define BAR()    __builtin_amdgcn_s_barrier()
#define SCHED0() __builtin_amdgcn_sched_barrier(0)

// ---------------- fused cast fp32 -> bf16 for x, Wqkv, Wout ----------------
__global__ __launch_bounds__(256) void cast_all(const float* __restrict__ x,
                                                const float* __restrict__ wq,
                                                const float* __restrict__ wo,
                                                unsigned short* __restrict__ xb,
                                                unsigned short* __restrict__ wqb,
                                                unsigned short* __restrict__ wob) {
    const size_t base = (size_t)blockIdx.x * 2048 + threadIdx.x;
#pragma unroll
    for (int it = 0; it < 8; ++it) {
        size_t i = base + (size_t)it * 256;
        const float4* s; ushort4* d; size_t off;
        if (i < 4194304)      { s = (const float4*)x;  d = (ushort4*)xb;  off = i; }
        else if (i < 4980736) { s = (const float4*)wq; d = (ushort4*)wqb; off = i - 4194304; }
        else                  { s = (const float4*)wo; d = (ushort4*)wob; off = i - 4980736; }
        float4 v = s[off];
        ushort4 o;
        o.x = f2bf(v.x); o.y = f2bf(v.y); o.z = f2bf(v.z); o.w = f2bf(v.w);
        d[off] = o;
    }
}

// ---------------- 256^2 single-sync deep-pipelined NT GEMM ----------------
// C[m,n] = sum_k A[m,k]*B[n,k] + bias[n]
// LDS half-tile = [128 rows][64 cols] bf16 = 16KB; chunk = 16B (8 bf16).
// Swizzle: LDS slot s at row r holds global chunk j = s ^ (r&7).
template<int OUTF32>
__global__ __launch_bounds__(512, 2) void gemm256(const unsigned short* __restrict__ A,
                                                  const unsigned short* __restrict__ B,
                                                  const float* __restrict__ bias,
                                                  unsigned short* __restrict__ Cb,
                                                  float* __restrict__ Cf,
                                                  int M, int N, int K, int NXT) {
    __shared__ __align__(16) unsigned short lds[2][2][2][8192]; // [buf][A/B][half][128*64]

    const int tid  = threadIdx.x;
    const int lane = tid & 63;
    const int wave = tid >> 6;
    const int wr = wave >> 2;        // 0..1  (M side)
    const int wc = wave & 3;         // 0..3  (N side)
    const int fr = lane & 15;
    const int fq = lane >> 4;
    const int frx = fr & 7;
    const int rot = (wave >> 2) & 1; // SIMD-partner stagger key (waves 0-3 vs 4-7)

    // T1: bijective XCD swizzle (grid size % 8 == 0 at all call sites)
    const int nwg  = gridDim.x;
    const int orig = blockIdx.x;
    const int wg   = (orig & 7) * (nwg >> 3) + (orig >> 3);
    const int tileM = (wg / NXT) * 256;
    const int tileN = (wg % NXT) * 256;

    // staging: thread covers chunks tid and tid+512 of a half-tile
    const int r8  = tid >> 3;                 // row 0..63 (first load), +64 second
    const int jsw = (tid & 7) ^ (r8 & 7);     // pre-swizzled global chunk index
    const unsigned short* Ap = A;
    const unsigned short* Bp = B;

#define STAGE(nb, OPp, HH, ktt) do {                                                   \
    const unsigned short* gb = (OPp) ? Bp : Ap;                                        \
    const int rb = ((OPp) ? tileN : tileM) + (HH) * 128 + r8;                          \
    const unsigned short* s0 = gb + (size_t)rb * K + (ktt) * 64 + jsw * 8;             \
    unsigned short* d0 = &lds[nb][OPp][HH][tid * 8];                                   \
    __builtin_amdgcn_global_load_lds((const __attribute__((address_space(1))) void*)s0,\
        (__attribute__((address_space(3))) void*)d0, 16, 0, 0);                        \
    __builtin_amdgcn_global_load_lds(                                                  \
        (const __attribute__((address_space(1))) void*)(s0 + (size_t)64 * K),          \
        (__attribute__((address_space(3))) void*)(d0 + 4096), 16, 0, 0);               \
} while (0)

// read A-half h of buffer bb into af (8 x b128)
#define READ_A(bb, h) do {                                                             \
    _Pragma("unroll") for (int i2 = 0; i2 < 4; ++i2) {                                 \
        const int ar = (wr * 64 + i2 * 16 + fr) * 64;                                  \
        af[i2][0] = *(const bf16x8*)&lds[bb][0][h][ar + ((fq ^ frx) << 3)];            \
        af[i2][1] = *(const bf16x8*)&lds[bb][0][h][ar + (((4 + fq) ^ frx) << 3)];      \
    }                                                                                  \
} while (0)

// read B-half g of buffer bb into bfr[2g..2g+1] (4 x b128)
#define READ_B(bb, g) do {                                                             \
    _Pragma("unroll") for (int j2 = 0; j2 < 2; ++j2) {                                 \
        const int br = (wc * 32 + j2 * 16 + fr) * 64;                                  \
        bfr[2*(g)+j2][0] = *(const bf16x8*)&lds[bb][1][g][br + ((fq ^ frx) << 3)];     \
        bfr[2*(g)+j2][1] = *(const bf16x8*)&lds[bb][1][g][br + (((4 + fq) ^ frx) << 3)];\
    }                                                                                  \
} while (0)

#define MFMA_Q(h, g) do {                                                              \
    __builtin_amdgcn_s_setprio(1);                                                     \
    _Pragma("unroll") for (int i2 = 0; i2 < 4; ++i2)                                   \
    _Pragma("unroll") for (int j2 = 0; j2 < 2; ++j2) {                                 \
        acc[(h)*4+i2][(g)*2+j2] = __builtin_amdgcn_mfma_f32_16x16x32_bf16(             \
            af[i2][0], bfr[2*(g)+j2][0], acc[(h)*4+i2][(g)*2+j2], 0, 0, 0);            \
        acc[(h)*4+i2][(g)*2+j2] = __builtin_amdgcn_mfma_f32_16x16x32_bf16(             \
            af[i2][1], bfr[2*(g)+j2][1], acc[(h)*4+i2][(g)*2+j2], 0, 0, 0);            \
    }                                                                                  \
    __builtin_amdgcn_s_setprio(0);                                                     \
} while (0)

    f32x4 acc[8][4];
#pragma unroll
    for (int i = 0; i < 8; ++i)
#pragma unroll
        for (int j = 0; j < 4; ++j) acc[i][j] = (f32x4){0.f, 0.f, 0.f, 0.f};

    // prologue: stage all 4 halves of tile 0 (8 loads) -> steady invariant E=8
    STAGE(0, 0, 0, 0);
    STAGE(0, 1, 0, 0);
    STAGE(0, 1, 1, 0);
    STAGE(0, 0, 1, 0);

    const int NT = K >> 6;
    int cur = 0;
    for (int kt = 0; kt < NT - 1; ++kt) {
        const int nb = cur ^ 1;
        BAR();                              // BAR1: close t-1's reads of nb
        STAGE(nb, 0, 0, kt + 1);            // A0(t+1)
        STAGE(nb, 1, 0, kt + 1);            // B0(t+1)   (out = 12)
        VMCNT4();                           // tile t's 8 loads landed (deep lead)
        BAR();                              // BAR2: publish tile t
        SCHED0();
        bf16x8 af[4][2], bfr[4][2];
        if (rot == 0) {
            READ_A(cur, 0); READ_B(cur, 0); READ_B(cur, 1);
            MFMA_Q(0, 0);
            STAGE(nb, 1, 1, kt + 1);        // B1(t+1)
            STAGE(nb, 0, 1, kt + 1);        // A1(t+1)   (out = 8)
            MFMA_Q(0, 1);
            READ_A(cur, 1);
            MFMA_Q(1, 0);
            MFMA_Q(1, 1);
        } else {
            READ_A(cur, 1); READ_B(cur, 0); READ_B(cur, 1);
            MFMA_Q(1, 0);
            STAGE(nb, 1, 1, kt + 1);        // B1(t+1)
            STAGE(nb, 0, 1, kt + 1);        // A1(t+1)   (out = 8)
            MFMA_Q(1, 1);
            READ_A(cur, 0);
            MFMA_Q(0, 0);
            MFMA_Q(0, 1);
        }
        cur = nb;
    }
    // last tile: no stages; drain its 8 loads once
    BAR();
    VMCNT0();
    BAR();
    SCHED0();
    {
        bf16x8 af[4][2], bfr[4][2];
        if (rot == 0) {
            READ_A(cur, 0); READ_B(cur, 0); READ_B(cur, 1);
            MFMA_Q(0, 0);
            MFMA_Q(0, 1);
            READ_A(cur, 1);
            MFMA_Q(1, 0);
            MFMA_Q(1, 1);
        } else {
            READ_A(cur, 1); READ_B(cur, 0); READ_B(cur, 1);
            MFMA_Q(1, 0);
            MFMA_Q(1, 1);
            READ_A(cur, 0);
            MFMA_Q(0, 0);
            MFMA_Q(0, 1);
        }
    }

    // epilogue: C/D layout col=lane&15, row=(lane>>4)*4+reg
#pragma unroll
    for (int i = 0; i < 8; ++i) {
        const int row = tileM + (i >> 2) * 128 + wr * 64 + (i & 3) * 16 + fq * 4;
#pragma unroll
        for (int j = 0; j < 4; ++j) {
            const int col = tileN + (j >> 1) * 128 + wc * 32 + (j & 1) * 16 + fr;
            const float bv = bias[col];
#pragma unroll
            for (int r = 0; r < 4; ++r) {
                const float v = acc[i][j][r] + bv;
                if (OUTF32) Cf[(size_t)(row + r) * N + col] = v;
                else        Cb[(size_t)(row + r) * N + col] = f2bf(v);
            }
        }
    }
#undef STAGE
#undef READ_A
#undef READ_B
#undef MFMA_Q
}

// ---------------- per-token head-attention ----------------
// One token per wave, 4 waves/block. qkv row layout: [3][16][64] bf16.
// LDS: Q/K rows 72-stride (conflict-free), V dense. No Pl array (26.6 KB
// block LDS -> 6 blocks/CU). Softmax kept in registers; PV via __shfl
// broadcast: P[h,g] lives in lane (h&3)*16+g, slot h>>2 (unnormalized e;
// normalize once by 1/s at the end).
// Writes the SCRAMBLED layout: scr[(b*4096 + 256*h + (l>>4))*1024 + (l&15)*64 + d]
__global__ __launch_bounds__(256) void attn_kernel(const unsigned short* __restrict__ qkv,
                                                   unsigned short* __restrict__ scr) {
    __shared__ __align__(16) unsigned short sbuf[4][3328];

    const int wave = threadIdx.x >> 6, lane = threadIdx.x & 63;
    const int token = blockIdx.x * 4 + wave;
    const int b = token >> 12, l = token & 4095;

    const unsigned short* src = qkv + (size_t)token * 3072;
    unsigned short* sw = sbuf[wave];
#pragma unroll
    for (int i = 0; i < 2; ++i) {
        const int c = lane + i * 64;           // chunk 0..127 (8 bf16 each)
        const int row = c >> 3, j8 = (c & 7) * 8;
        *(bf16x8*)&sw[row * 72 + j8]        = *(const bf16x8*)&src[c * 8];          // Q
        *(bf16x8*)&sw[1152 + row * 72 + j8] = *(const bf16x8*)&src[1024 + c * 8];   // K
        *(bf16x8*)&sw[2304 + c * 8]         = *(const bf16x8*)&src[2048 + c * 8];   // V
    }
    __syncthreads();

    // scores: lane handles (h,g) pairs p = r*64+lane; p == h*16+g directly
    float sv[4];
#pragma unroll
    for (int r = 0; r < 4; ++r) {
        const int p = r * 64 + lane;
        const int h = p >> 4, g = p & 15;
        float acc = 0.f;
#pragma unroll
        for (int d8 = 0; d8 < 8; ++d8) {
            bf16x8 qa = *(const bf16x8*)&sw[h * 72 + d8 * 8];
            bf16x8 kb = *(const bf16x8*)&sw[1152 + g * 72 + d8 * 8];
#pragma unroll
            for (int j = 0; j < 8; ++j)
                acc += bf2f((unsigned short)qa[j]) * bf2f((unsigned short)kb[j]);
        }
        sv[r] = acc * 0.125f;   // scale = 64^-0.5
    }

    // softmax over g (16-lane groups), kept in registers: ev = e, rs = 1/sum(e)
    float ev[4], rs[4];
#pragma unroll
    for (int r = 0; r < 4; ++r) {
        float m = sv[r];
        m = fmaxf(m, __shfl_xor(m, 1));
        m = fmaxf(m, __shfl_xor(m, 2));
        m = fmaxf(m, __shfl_xor(m, 4));
        m = fmaxf(m, __shfl_xor(m, 8));
        float e = __expf(sv[r] - m);
        float s = e;
        s += __shfl_xor(s, 1);
        s += __shfl_xor(s, 2);
        s += __shfl_xor(s, 4);
        s += __shfl_xor(s, 8);
        ev[r] = e;
        rs[r] = 1.0f / s;
    }

    // PV: head h per rep, lane = d. V rows from LDS; P via shfl broadcast.
    float vreg[16];
#pragma unroll
    for (int g = 0; g < 16; ++g) vreg[g] = bf2f(sw[2304 + g * 64 + lane]);

    const int q_ = l >> 4, j = l & 15;
    const size_t base = ((size_t)b * 4096 + q_) * 1024 + j * 64 + lane;
#pragma unroll
    for (int h = 0; h < 16; ++h) {
        const int rr = h >> 2, lb = (h & 3) << 4;
        float acc = 0.f;
#pragma unroll
        for (int g = 0; g < 16; ++g) acc += __shfl(ev[rr], lb + g) * vreg[g];
        const float o = acc * __shfl(rs[rr], lb);
        scr[base + (size_t)h * 256 * 1024] = f2bf(o);
    }
}

// ---------------- launch ----------------
extern "C" void kernel_launch(void* const* d_in, const int* in_sizes, int n_in,
                              void* d_out, int out_size, void* d_ws, size_t ws_size,
                              hipStream_t stream) {
    const float* x    = (const float*)d_in[0];   // [4,4096,1024]
    const float* Wqkv = (const float*)d_in[1];   // [3072,1024]
    const float* bqkv = (const float*)d_in[2];   // [3072]
    const float* Wout = (const float*)d_in[3];   // [1024,1024]
    const float* bout = (const float*)d_in[4];   // [1024]
    float* out = (float*)d_out;                  // [4,4096,1024] fp32

    char* ws = (char*)d_ws;
    unsigned short* xb   = (unsigned short*)(ws);
    unsigned short* wqb  = (unsigned short*)(ws + 33554432);
    unsigned short* wob  = (unsigned short*)(ws + 39845888);
    unsigned short* qkvb = (unsigned short*)(ws + 41943040);
    unsigned short* scr  = (unsigned short*)(ws + 142606336);

    cast_all<<<2560, 256, 0, stream>>>(x, Wqkv, Wout, xb, wqb, wob);

    // qkv = x @ Wqkv^T + bqkv  (M=16384, N=3072, K=1024), bf16 out; 768 blocks
    gemm256<0><<<768, 512, 0, stream>>>(xb, wqb, bqkv, qkvb, nullptr, 16384, 3072, 1024, 12);

    // per-token head attention -> scrambled layout
    attn_kernel<<<4096, 256, 0, stream>>>(qkvb, scr);

    // out = scr @ Wout^T + bout  (M=16384, N=1024, K=1024), fp32 out; 256 blocks
    gemm256<1><<<256, 512, 0, stream>>>(scr, wob, bout, nullptr, out, 16384, 1024, 1024, 4);
}

// Round 10
// 206.218 us; speedup vs baseline: 1.1369x; 1.1369x over previous
//
#include <hip/hip_runtime.h>
#include <hip/hip_bf16.h>

// B=4, L=4096, C=1024, H=16, D=64
// GEMM1: qkv = x@Wqkv^T+b  (M=16384,N=3072,K=1024)  -> bf16
// attn: per-token 16x16 head-attention, writes scrambled layout
// GEMM2: out = scr@Wout^T+b (M=16384,N=1024,K=1024) -> fp32
//
// Round-10: REVERT R9 (stagger + shfl-PV both regressed). gemm256 keeps the
// R7 single-sync skeleton (BAR1 / stage A0,B0 / vmcnt(4) / BAR2 / mid-stage
// B1,A1; XOR swizzle T2; XCD swizzle T1; setprio T5) but switches the MFMA
// from 16x16x32 (2176 TF ceiling) to 32x32x16 (2382-2495 TF, m06/m119):
// same acc budget (128 regs = 4x2 f32x16), HALF the MFMA instructions
// (32/K-tile/wave), 4 kk-phases x {6 ds_read_b128 + 8 MFMA}.
// Layouts: A row=lane&31, k=(lane>>5)*8+e; B col=lane&31 same k;
// C/D col=lane&31, row=(reg&3)+8*(reg>>2)+4*(lane>>5)  [m74/m101].
// attn: R8 version (72-stride Q/K, Pl in LDS).

typedef __attribute__((ext_vector_type(8)))  short bf16x8;
typedef __attribute__((ext_vector_type(4)))  float f32x4;
typedef __attribute__((ext_vector_type(16))) float f32x16;

__device__ __forceinline__ float bf2f(unsigned short u) {
    union { unsigned int i; float f; } x;
    x.i = ((unsigned int)u) << 16;
    return x.f;
}
__device__ __forceinline__ unsigned short f2bf(float f) {
    unsigned int u = __float_as_uint(f);
    u = (u + 0x7FFFu + ((u >> 16) & 1u)) >> 16;   // RNE
    return (unsigned short)u;
}

#define VMCNT4() asm volatile("s_waitcnt vmcnt(4)" ::: "memory")
#define VMCNT0() asm volatile("s_waitcnt vmcnt(0)" ::: "memory")
#define BAR()    __builtin_amdgcn_s_barrier()
#define SCHED0() __builtin_amdgcn_sched_barrier(0)

// ---------------- fused cast fp32 -> bf16 for x, Wqkv, Wout ----------------
__global__ __launch_bounds__(256) void cast_all(const float* __restrict__ x,
                                                const float* __restrict__ wq,
                                                const float* __restrict__ wo,
                                                unsigned short* __restrict__ xb,
                                                unsigned short* __restrict__ wqb,
                                                unsigned short* __restrict__ wob) {
    const size_t base = (size_t)blockIdx.x * 2048 + threadIdx.x;
#pragma unroll
    for (int it = 0; it < 8; ++it) {
        size_t i = base + (size_t)it * 256;
        const float4* s; ushort4* d; size_t off;
        if (i < 4194304)      { s = (const float4*)x;  d = (ushort4*)xb;  off = i; }
        else if (i < 4980736) { s = (const float4*)wq; d = (ushort4*)wqb; off = i - 4194304; }
        else                  { s = (const float4*)wo; d = (ushort4*)wob; off = i - 4980736; }
        float4 v = s[off];
        ushort4 o;
        o.x = f2bf(v.x); o.y = f2bf(v.y); o.z = f2bf(v.z); o.w = f2bf(v.w);
        d[off] = o;
    }
}

// ---------------- 256^2 single-sync NT GEMM, 32x32x16 MFMA ----------------
// C[m,n] = sum_k A[m,k]*B[n,k] + bias[n]
// LDS half-tile = [128 rows][64 cols] bf16 = 16KB; chunk = 16B (8 bf16).
// Swizzle: LDS slot s at row r holds global chunk j = s ^ (r&7).
// Wave (wr,wc) owns rows {0,128}+wr*64+(m&1)*32, cols n*128+wc*32.
template<int OUTF32>
__global__ __launch_bounds__(512, 2) void gemm256(const unsigned short* __restrict__ A,
                                                  const unsigned short* __restrict__ B,
                                                  const float* __restrict__ bias,
                                                  unsigned short* __restrict__ Cb,
                                                  float* __restrict__ Cf,
                                                  int M, int N, int K, int NXT) {
    __shared__ __align__(16) unsigned short lds[2][2][2][8192]; // [buf][A/B][half][128*64]

    const int tid  = threadIdx.x;
    const int lane = tid & 63;
    const int wave = tid >> 6;
    const int wr = wave >> 2;        // 0..1  (M side)
    const int wc = wave & 3;         // 0..3  (N side)
    const int l31 = lane & 31;       // row/col within 32-frag
    const int kc  = lane >> 5;       // k-chunk selector (0/1)

    // T1: bijective XCD swizzle (grid size % 8 == 0 at all call sites)
    const int nwg  = gridDim.x;
    const int orig = blockIdx.x;
    const int wg   = (orig & 7) * (nwg >> 3) + (orig >> 3);
    const int tileM = (wg / NXT) * 256;
    const int tileN = (wg % NXT) * 256;

    // staging: thread covers chunks tid and tid+512 of a half-tile
    const int r8  = tid >> 3;                 // row 0..63 (first load), +64 second
    const int jsw = (tid & 7) ^ (r8 & 7);     // pre-swizzled global chunk index
    const unsigned short* Ap = A;
    const unsigned short* Bp = B;

#define STAGE(nb, OPp, HH, ktt) do {                                                   \
    const unsigned short* gb = (OPp) ? Bp : Ap;                                        \
    const int rb = ((OPp) ? tileN : tileM) + (HH) * 128 + r8;                          \
    const unsigned short* s0 = gb + (size_t)rb * K + (ktt) * 64 + jsw * 8;             \
    unsigned short* d0 = &lds[nb][OPp][HH][tid * 8];                                   \
    __builtin_amdgcn_global_load_lds((const __attribute__((address_space(1))) void*)s0,\
        (__attribute__((address_space(3))) void*)d0, 16, 0, 0);                        \
    __builtin_amdgcn_global_load_lds(                                                  \
        (const __attribute__((address_space(1))) void*)(s0 + (size_t)64 * K),          \
        (__attribute__((address_space(3))) void*)(d0 + 4096), 16, 0, 0);               \
} while (0)

// read all fragments for k-step kk (4 A + 2 B = 6 x ds_read_b128)
#define READ_K(bb, kk) do {                                                            \
    _Pragma("unroll") for (int m = 0; m < 4; ++m) {                                    \
        const int rl = wr * 64 + (m & 1) * 32 + l31;                                   \
        const int c  = (kk) * 2 + kc;                                                  \
        afk[m] = *(const bf16x8*)&lds[bb][0][m >> 1][rl * 64 + ((c ^ (rl & 7)) << 3)]; \
    }                                                                                  \
    _Pragma("unroll") for (int n = 0; n < 2; ++n) {                                    \
        const int cl = wc * 32 + l31;                                                  \
        const int c  = (kk) * 2 + kc;                                                  \
        bfk[n] = *(const bf16x8*)&lds[bb][1][n][cl * 64 + ((c ^ (cl & 7)) << 3)];      \
    }                                                                                  \
} while (0)

#define MFMA_K() do {                                                                  \
    __builtin_amdgcn_s_setprio(1);                                                     \
    _Pragma("unroll") for (int m = 0; m < 4; ++m)                                      \
    _Pragma("unroll") for (int n = 0; n < 2; ++n)                                      \
        acc[m][n] = __builtin_amdgcn_mfma_f32_32x32x16_bf16(afk[m], bfk[n],            \
                                                            acc[m][n], 0, 0, 0);       \
    __builtin_amdgcn_s_setprio(0);                                                     \
} while (0)

    f32x16 acc[4][2];
#pragma unroll
    for (int m = 0; m < 4; ++m)
#pragma unroll
        for (int n = 0; n < 2; ++n)
#pragma unroll
            for (int r = 0; r < 16; ++r) acc[m][n][r] = 0.f;

    // prologue: stage all 4 halves of tile 0 (8 loads) -> steady invariant E=8
    STAGE(0, 0, 0, 0);
    STAGE(0, 1, 0, 0);
    STAGE(0, 1, 1, 0);
    STAGE(0, 0, 1, 0);

    const int NT = K >> 6;
    int cur = 0;
    for (int kt = 0; kt < NT - 1; ++kt) {
        const int nb = cur ^ 1;
        BAR();                              // BAR1: close t-1's reads of nb
        STAGE(nb, 0, 0, kt + 1);            // A0(t+1)
        STAGE(nb, 1, 0, kt + 1);            // B0(t+1)   (out = 12)
        VMCNT4();                           // tile t's 8 loads landed (deep lead)
        BAR();                              // BAR2: publish tile t
        SCHED0();
        bf16x8 afk[4], bfk[2];
        READ_K(cur, 0); MFMA_K();
        STAGE(nb, 1, 1, kt + 1);            // B1(t+1)
        STAGE(nb, 0, 1, kt + 1);            // A1(t+1)   (out = 8)
        READ_K(cur, 1); MFMA_K();
        READ_K(cur, 2); MFMA_K();
        READ_K(cur, 3); MFMA_K();
        cur = nb;
    }
    // last tile: no stages; drain its 8 loads once
    BAR();
    VMCNT0();
    BAR();
    SCHED0();
    {
        bf16x8 afk[4], bfk[2];
        READ_K(cur, 0); MFMA_K();
        READ_K(cur, 1); MFMA_K();
        READ_K(cur, 2); MFMA_K();
        READ_K(cur, 3); MFMA_K();
    }

    // epilogue: 32x32 C/D layout col=lane&31, row=(reg&3)+8*(reg>>2)+4*kc
#pragma unroll
    for (int n = 0; n < 2; ++n) {
        const int col = tileN + n * 128 + wc * 32 + l31;
        const float bv = bias[col];
#pragma unroll
        for (int m = 0; m < 4; ++m) {
            const int rbase = tileM + (m >> 1) * 128 + wr * 64 + (m & 1) * 32 + 4 * kc;
#pragma unroll
            for (int r = 0; r < 16; ++r) {
                const int row = rbase + (r & 3) + 8 * (r >> 2);
                const float v = acc[m][n][r] + bv;
                if (OUTF32) Cf[(size_t)row * N + col] = v;
                else        Cb[(size_t)row * N + col] = f2bf(v);
            }
        }
    }
#undef STAGE
#undef READ_K
#undef MFMA_K
}

// ---------------- per-token head-attention (R8 version) ----------------
// One token per wave, 4 waves/block. qkv row layout: [3][16][64] bf16.
// LDS: Q rows 72-stride @0, K rows 72-stride @1152, V dense @2304.
// Writes the SCRAMBLED layout: scr[(b*4096 + 256*h + (l>>4))*1024 + (l&15)*64 + d]
__global__ __launch_bounds__(256) void attn_kernel(const unsigned short* __restrict__ qkv,
                                                   unsigned short* __restrict__ scr) {
    __shared__ __align__(16) unsigned short sbuf[4][3328];
    __shared__ float Pl[4][256];

    const int wave = threadIdx.x >> 6, lane = threadIdx.x & 63;
    const int token = blockIdx.x * 4 + wave;
    const int b = token >> 12, l = token & 4095;

    const unsigned short* src = qkv + (size_t)token * 3072;
    unsigned short* sw = sbuf[wave];
#pragma unroll
    for (int i = 0; i < 2; ++i) {
        const int c = lane + i * 64;           // chunk 0..127 (8 bf16 each)
        const int row = c >> 3, j8 = (c & 7) * 8;
        *(bf16x8*)&sw[row * 72 + j8]        = *(const bf16x8*)&src[c * 8];          // Q
        *(bf16x8*)&sw[1152 + row * 72 + j8] = *(const bf16x8*)&src[1024 + c * 8];   // K
        *(bf16x8*)&sw[2304 + c * 8]         = *(const bf16x8*)&src[2048 + c * 8];   // V
    }
    __syncthreads();

    float sv[4];
#pragma unroll
    for (int r = 0; r < 4; ++r) {
        const int p = r * 64 + lane;
        const int h = p >> 4, g = p & 15;
        float acc = 0.f;
#pragma unroll
        for (int d8 = 0; d8 < 8; ++d8) {
            bf16x8 qa = *(const bf16x8*)&sw[h * 72 + d8 * 8];
            bf16x8 kb = *(const bf16x8*)&sw[1152 + g * 72 + d8 * 8];
#pragma unroll
            for (int j = 0; j < 8; ++j)
                acc += bf2f((unsigned short)qa[j]) * bf2f((unsigned short)kb[j]);
        }
        sv[r] = acc * 0.125f;   // scale = 64^-0.5
    }

#pragma unroll
    for (int r = 0; r < 4; ++r) {
        float m = sv[r];
        m = fmaxf(m, __shfl_xor(m, 1));
        m = fmaxf(m, __shfl_xor(m, 2));
        m = fmaxf(m, __shfl_xor(m, 4));
        m = fmaxf(m, __shfl_xor(m, 8));
        float e = __expf(sv[r] - m);
        float s = e;
        s += __shfl_xor(s, 1);
        s += __shfl_xor(s, 2);
        s += __shfl_xor(s, 4);
        s += __shfl_xor(s, 8);
        Pl[wave][r * 64 + lane] = e / s;
    }
    __syncthreads();

    float vreg[16];
#pragma unroll
    for (int g = 0; g < 16; ++g) vreg[g] = bf2f(sw[2304 + g * 64 + lane]);

    const int q_ = l >> 4, j = l & 15;
    const size_t base = ((size_t)b * 4096 + q_) * 1024 + j * 64 + lane;
#pragma unroll
    for (int h = 0; h < 16; ++h) {
        float acc = 0.f;
#pragma unroll
        for (int g = 0; g < 16; ++g) acc += Pl[wave][h * 16 + g] * vreg[g];
        scr[base + (size_t)h * 256 * 1024] = f2bf(acc);
    }
}

// ---------------- launch ----------------
extern "C" void kernel_launch(void* const* d_in, const int* in_sizes, int n_in,
                              void* d_out, int out_size, void* d_ws, size_t ws_size,
                              hipStream_t stream) {
    const float* x    = (const float*)d_in[0];   // [4,4096,1024]
    const float* Wqkv = (const float*)d_in[1];   // [3072,1024]
    const float* bqkv = (const float*)d_in[2];   // [3072]
    const float* Wout = (const float*)d_in[3];   // [1024,1024]
    const float* bout = (const float*)d_in[4];   // [1024]
    float* out = (float*)d_out;                  // [4,4096,1024] fp32

    char* ws = (char*)d_ws;
    unsigned short* xb   = (unsigned short*)(ws);
    unsigned short* wqb  = (unsigned short*)(ws + 33554432);
    unsigned short* wob  = (unsigned short*)(ws + 39845888);
    unsigned short* qkvb = (unsigned short*)(ws + 41943040);
    unsigned short* scr  = (unsigned short*)(ws + 142606336);

    cast_all<<<2560, 256, 0, stream>>>(x, Wqkv, Wout, xb, wqb, wob);

    // qkv = x @ Wqkv^T + bqkv  (M=16384, N=3072, K=1024), bf16 out; 768 blocks
    gemm256<0><<<768, 512, 0, stream>>>(xb, wqb, bqkv, qkvb, nullptr, 16384, 3072, 1024, 12);

    // per-token head attention -> scrambled layout
    attn_kernel<<<4096, 256, 0, stream>>>(qkvb, scr);

    // out = scr @ Wout^T + bout  (M=16384, N=1024, K=1024), fp32 out; 256 blocks
    gemm256<1><<<256, 512, 0, stream>>>(scr, wob, bout, nullptr, out, 16384, 1024, 1024, 4);
}

// Round 11
// 196.003 us; speedup vs baseline: 1.1962x; 1.0521x over previous
//
#include <hip/hip_runtime.h>
#include <hip/hip_bf16.h>

// B=4, L=4096, C=1024, H=16, D=64
// GEMM1: qkv = x@Wqkv^T+b  (M=16384,N=3072,K=1024)  -> bf16
// attn: per-token 16x16 head-attention, writes scrambled layout
// GEMM2: out = scr@Wout^T+b (M=16384,N=1024,K=1024) -> fp32
//
// Round-11: REVERT to proven best (R7 gemm256 16x16x32 single-sync + R8 attn
// = 198.65us). R10's 32x32x16 experiment is closed: its fragment reads span
// 32 rows x one 16B chunk => 4 lanes/bank-group alias (9.4M conflicts),
// unfixable by swizzle in a 64-col LDS tile; the +10% MFMA rate is eaten by
// the 1.58x LDS-read penalty (m136). 16x16x32 spans 16 rows => 2-way = free.
// G1 campaign summary: R3 win; R5/R6/R7 schedule variants null (112-115us);
// R4/R9/R10 structure changes regressed. This config = plateau of the
// plain-HIP 256^2 template at K=1024.

typedef __attribute__((ext_vector_type(8))) short bf16x8;
typedef __attribute__((ext_vector_type(4))) float f32x4;

__device__ __forceinline__ float bf2f(unsigned short u) {
    union { unsigned int i; float f; } x;
    x.i = ((unsigned int)u) << 16;
    return x.f;
}
__device__ __forceinline__ unsigned short f2bf(float f) {
    unsigned int u = __float_as_uint(f);
    u = (u + 0x7FFFu + ((u >> 16) & 1u)) >> 16;   // RNE
    return (unsigned short)u;
}

#define VMCNT4() asm volatile("s_waitcnt vmcnt(4)" ::: "memory")
#define VMCNT0() asm volatile("s_waitcnt vmcnt(0)" ::: "memory")
#define BAR()    __builtin_amdgcn_s_barrier()
#define SCHED0() __builtin_amdgcn_sched_barrier(0)

// ---------------- fused cast fp32 -> bf16 for x, Wqkv, Wout ----------------
__global__ __launch_bounds__(256) void cast_all(const float* __restrict__ x,
                                                const float* __restrict__ wq,
                                                const float* __restrict__ wo,
                                                unsigned short* __restrict__ xb,
                                                unsigned short* __restrict__ wqb,
                                                unsigned short* __restrict__ wob) {
    const size_t base = (size_t)blockIdx.x * 2048 + threadIdx.x;
#pragma unroll
    for (int it = 0; it < 8; ++it) {
        size_t i = base + (size_t)it * 256;
        const float4* s; ushort4* d; size_t off;
        if (i < 4194304)      { s = (const float4*)x;  d = (ushort4*)xb;  off = i; }
        else if (i < 4980736) { s = (const float4*)wq; d = (ushort4*)wqb; off = i - 4194304; }
        else                  { s = (const float4*)wo; d = (ushort4*)wob; off = i - 4980736; }
        float4 v = s[off];
        ushort4 o;
        o.x = f2bf(v.x); o.y = f2bf(v.y); o.z = f2bf(v.z); o.w = f2bf(v.w);
        d[off] = o;
    }
}

// ---------------- 256^2 single-sync deep-pipelined NT GEMM ----------------
// C[m,n] = sum_k A[m,k]*B[n,k] + bias[n]
// LDS half-tile = [128 rows][64 cols] bf16 = 16KB; chunk = 16B (8 bf16).
// Swizzle: LDS slot s at row r holds global chunk j = s ^ (r&7).
template<int OUTF32>
__global__ __launch_bounds__(512, 2) void gemm256(const unsigned short* __restrict__ A,
                                                  const unsigned short* __restrict__ B,
                                                  const float* __restrict__ bias,
                                                  unsigned short* __restrict__ Cb,
                                                  float* __restrict__ Cf,
                                                  int M, int N, int K, int NXT) {
    __shared__ __align__(16) unsigned short lds[2][2][2][8192]; // [buf][A/B][half][128*64]

    const int tid  = threadIdx.x;
    const int lane = tid & 63;
    const int wave = tid >> 6;
    const int wr = wave >> 2;        // 0..1  (M side)
    const int wc = wave & 3;         // 0..3  (N side)
    const int fr = lane & 15;
    const int fq = lane >> 4;
    const int frx = fr & 7;

    // T1: bijective XCD swizzle (grid size % 8 == 0 at all call sites)
    const int nwg  = gridDim.x;
    const int orig = blockIdx.x;
    const int wg   = (orig & 7) * (nwg >> 3) + (orig >> 3);
    const int tileM = (wg / NXT) * 256;
    const int tileN = (wg % NXT) * 256;

    // staging: thread covers chunks tid and tid+512 of a half-tile
    const int r8  = tid >> 3;                 // row 0..63 (first load), +64 second
    const int jsw = (tid & 7) ^ (r8 & 7);     // pre-swizzled global chunk index
    const unsigned short* Ap = A;
    const unsigned short* Bp = B;

#define STAGE(nb, OPp, HH, ktt) do {                                                   \
    const unsigned short* gb = (OPp) ? Bp : Ap;                                        \
    const int rb = ((OPp) ? tileN : tileM) + (HH) * 128 + r8;                          \
    const unsigned short* s0 = gb + (size_t)rb * K + (ktt) * 64 + jsw * 8;             \
    unsigned short* d0 = &lds[nb][OPp][HH][tid * 8];                                   \
    __builtin_amdgcn_global_load_lds((const __attribute__((address_space(1))) void*)s0,\
        (__attribute__((address_space(3))) void*)d0, 16, 0, 0);                        \
    __builtin_amdgcn_global_load_lds(                                                  \
        (const __attribute__((address_space(1))) void*)(s0 + (size_t)64 * K),          \
        (__attribute__((address_space(3))) void*)(d0 + 4096), 16, 0, 0);               \
} while (0)

// read A-half h of buffer bb into af (8 x b128)
#define READ_A(bb, h) do {                                                             \
    _Pragma("unroll") for (int i2 = 0; i2 < 4; ++i2) {                                 \
        const int ar = (wr * 64 + i2 * 16 + fr) * 64;                                  \
        af[i2][0] = *(const bf16x8*)&lds[bb][0][h][ar + ((fq ^ frx) << 3)];            \
        af[i2][1] = *(const bf16x8*)&lds[bb][0][h][ar + (((4 + fq) ^ frx) << 3)];      \
    }                                                                                  \
} while (0)

// read B-half g of buffer bb into bfr[2g..2g+1] (4 x b128)
#define READ_B(bb, g) do {                                                             \
    _Pragma("unroll") for (int j2 = 0; j2 < 2; ++j2) {                                 \
        const int br = (wc * 32 + j2 * 16 + fr) * 64;                                  \
        bfr[2*(g)+j2][0] = *(const bf16x8*)&lds[bb][1][g][br + ((fq ^ frx) << 3)];     \
        bfr[2*(g)+j2][1] = *(const bf16x8*)&lds[bb][1][g][br + (((4 + fq) ^ frx) << 3)];\
    }                                                                                  \
} while (0)

#define MFMA_Q(h, g) do {                                                              \
    __builtin_amdgcn_s_setprio(1);                                                     \
    _Pragma("unroll") for (int i2 = 0; i2 < 4; ++i2)                                   \
    _Pragma("unroll") for (int j2 = 0; j2 < 2; ++j2) {                                 \
        acc[(h)*4+i2][(g)*2+j2] = __builtin_amdgcn_mfma_f32_16x16x32_bf16(             \
            af[i2][0], bfr[2*(g)+j2][0], acc[(h)*4+i2][(g)*2+j2], 0, 0, 0);            \
        acc[(h)*4+i2][(g)*2+j2] = __builtin_amdgcn_mfma_f32_16x16x32_bf16(             \
            af[i2][1], bfr[2*(g)+j2][1], acc[(h)*4+i2][(g)*2+j2], 0, 0, 0);            \
    }                                                                                  \
    __builtin_amdgcn_s_setprio(0);                                                     \
} while (0)

    f32x4 acc[8][4];
#pragma unroll
    for (int i = 0; i < 8; ++i)
#pragma unroll
        for (int j = 0; j < 4; ++j) acc[i][j] = (f32x4){0.f, 0.f, 0.f, 0.f};

    // prologue: stage all 4 halves of tile 0 (8 loads) -> steady invariant E=8
    STAGE(0, 0, 0, 0);
    STAGE(0, 1, 0, 0);
    STAGE(0, 1, 1, 0);
    STAGE(0, 0, 1, 0);

    const int NT = K >> 6;
    int cur = 0;
    for (int kt = 0; kt < NT - 1; ++kt) {
        const int nb = cur ^ 1;
        BAR();                              // BAR1: close t-1's reads of nb
        STAGE(nb, 0, 0, kt + 1);            // A0(t+1)
        STAGE(nb, 1, 0, kt + 1);            // B0(t+1)   (out = 12)
        VMCNT4();                           // tile t's 8 loads landed (deep lead)
        BAR();                              // BAR2: publish tile t
        SCHED0();
        bf16x8 af[4][2], bfr[4][2];
        READ_A(cur, 0); READ_B(cur, 0); READ_B(cur, 1);
        MFMA_Q(0, 0);
        STAGE(nb, 1, 1, kt + 1);            // B1(t+1)
        STAGE(nb, 0, 1, kt + 1);            // A1(t+1)   (out = 8)
        MFMA_Q(0, 1);
        READ_A(cur, 1);
        MFMA_Q(1, 0);
        MFMA_Q(1, 1);
        cur = nb;
    }
    // last tile: no stages; drain its 8 loads once
    BAR();
    VMCNT0();
    BAR();
    SCHED0();
    {
        bf16x8 af[4][2], bfr[4][2];
        READ_A(cur, 0); READ_B(cur, 0); READ_B(cur, 1);
        MFMA_Q(0, 0);
        MFMA_Q(0, 1);
        READ_A(cur, 1);
        MFMA_Q(1, 0);
        MFMA_Q(1, 1);
    }

    // epilogue: C/D layout col=lane&15, row=(lane>>4)*4+reg
#pragma unroll
    for (int i = 0; i < 8; ++i) {
        const int row = tileM + (i >> 2) * 128 + wr * 64 + (i & 3) * 16 + fq * 4;
#pragma unroll
        for (int j = 0; j < 4; ++j) {
            const int col = tileN + (j >> 1) * 128 + wc * 32 + (j & 1) * 16 + fr;
            const float bv = bias[col];
#pragma unroll
            for (int r = 0; r < 4; ++r) {
                const float v = acc[i][j][r] + bv;
                if (OUTF32) Cf[(size_t)(row + r) * N + col] = v;
                else        Cb[(size_t)(row + r) * N + col] = f2bf(v);
            }
        }
    }
#undef STAGE
#undef READ_A
#undef READ_B
#undef MFMA_Q
}

// ---------------- per-token head-attention (R8 version) ----------------
// One token per wave, 4 waves/block. qkv row layout: [3][16][64] bf16.
// LDS: Q rows 72-stride @0, K rows 72-stride @1152, V dense @2304.
// Writes the SCRAMBLED layout: scr[(b*4096 + 256*h + (l>>4))*1024 + (l&15)*64 + d]
__global__ __launch_bounds__(256) void attn_kernel(const unsigned short* __restrict__ qkv,
                                                   unsigned short* __restrict__ scr) {
    __shared__ __align__(16) unsigned short sbuf[4][3328];
    __shared__ float Pl[4][256];

    const int wave = threadIdx.x >> 6, lane = threadIdx.x & 63;
    const int token = blockIdx.x * 4 + wave;
    const int b = token >> 12, l = token & 4095;

    const unsigned short* src = qkv + (size_t)token * 3072;
    unsigned short* sw = sbuf[wave];
#pragma unroll
    for (int i = 0; i < 2; ++i) {
        const int c = lane + i * 64;           // chunk 0..127 (8 bf16 each)
        const int row = c >> 3, j8 = (c & 7) * 8;
        *(bf16x8*)&sw[row * 72 + j8]        = *(const bf16x8*)&src[c * 8];          // Q
        *(bf16x8*)&sw[1152 + row * 72 + j8] = *(const bf16x8*)&src[1024 + c * 8];   // K
        *(bf16x8*)&sw[2304 + c * 8]         = *(const bf16x8*)&src[2048 + c * 8];   // V
    }
    __syncthreads();

    float sv[4];
#pragma unroll
    for (int r = 0; r < 4; ++r) {
        const int p = r * 64 + lane;
        const int h = p >> 4, g = p & 15;
        float acc = 0.f;
#pragma unroll
        for (int d8 = 0; d8 < 8; ++d8) {
            bf16x8 qa = *(const bf16x8*)&sw[h * 72 + d8 * 8];
            bf16x8 kb = *(const bf16x8*)&sw[1152 + g * 72 + d8 * 8];
#pragma unroll
            for (int j = 0; j < 8; ++j)
                acc += bf2f((unsigned short)qa[j]) * bf2f((unsigned short)kb[j]);
        }
        sv[r] = acc * 0.125f;   // scale = 64^-0.5
    }

#pragma unroll
    for (int r = 0; r < 4; ++r) {
        float m = sv[r];
        m = fmaxf(m, __shfl_xor(m, 1));
        m = fmaxf(m, __shfl_xor(m, 2));
        m = fmaxf(m, __shfl_xor(m, 4));
        m = fmaxf(m, __shfl_xor(m, 8));
        float e = __expf(sv[r] - m);
        float s = e;
        s += __shfl_xor(s, 1);
        s += __shfl_xor(s, 2);
        s += __shfl_xor(s, 4);
        s += __shfl_xor(s, 8);
        Pl[wave][r * 64 + lane] = e / s;
    }
    __syncthreads();

    float vreg[16];
#pragma unroll
    for (int g = 0; g < 16; ++g) vreg[g] = bf2f(sw[2304 + g * 64 + lane]);

    const int q_ = l >> 4, j = l & 15;
    const size_t base = ((size_t)b * 4096 + q_) * 1024 + j * 64 + lane;
#pragma unroll
    for (int h = 0; h < 16; ++h) {
        float acc = 0.f;
#pragma unroll
        for (int g = 0; g < 16; ++g) acc += Pl[wave][h * 16 + g] * vreg[g];
        scr[base + (size_t)h * 256 * 1024] = f2bf(acc);
    }
}

// ---------------- launch ----------------
extern "C" void kernel_launch(void* const* d_in, const int* in_sizes, int n_in,
                              void* d_out, int out_size, void* d_ws, size_t ws_size,
                              hipStream_t stream) {
    const float* x    = (const float*)d_in[0];   // [4,4096,1024]
    const float* Wqkv = (const float*)d_in[1];   // [3072,1024]
    const float* bqkv = (const float*)d_in[2];   // [3072]
    const float* Wout = (const float*)d_in[3];   // [1024,1024]
    const float* bout = (const float*)d_in[4];   // [1024]
    float* out = (float*)d_out;                  // [4,4096,1024] fp32

    char* ws = (char*)d_ws;
    unsigned short* xb   = (unsigned short*)(ws);
    unsigned short* wqb  = (unsigned short*)(ws + 33554432);
    unsigned short* wob  = (unsigned short*)(ws + 39845888);
    unsigned short* qkvb = (unsigned short*)(ws + 41943040);
    unsigned short* scr  = (unsigned short*)(ws + 142606336);

    cast_all<<<2560, 256, 0, stream>>>(x, Wqkv, Wout, xb, wqb, wob);

    // qkv = x @ Wqkv^T + bqkv  (M=16384, N=3072, K=1024), bf16 out; 768 blocks
    gemm256<0><<<768, 512, 0, stream>>>(xb, wqb, bqkv, qkvb, nullptr, 16384, 3072, 1024, 12);

    // per-token head attention -> scrambled layout
    attn_kernel<<<4096, 256, 0, stream>>>(qkvb, scr);

    // out = scr @ Wout^T + bout  (M=16384, N=1024, K=1024), fp32 out; 256 blocks
    gemm256<1><<<256, 512, 0, stream>>>(scr, wob, bout, nullptr, out, 16384, 1024, 1024, 4);
}